// Round 1
// baseline (10.571 us; speedup 1.0000x reference)
//
#include <hip/hip_runtime.h>

// out[b, 0:256]  = x0[b,i] >= 0 ? x0[b,i]*max(x1[b,:]) : x0[b,i]*min(x1[b,:])
// out[b, 256:384] = x2[b, :]
// B=4096, D1=D2=256, F=128, out row stride = 384 floats.

__global__ __launch_bounds__(256) void pairwise_max_kernel(
    const float* __restrict__ x0,
    const float* __restrict__ x1,
    const float* __restrict__ x2,
    float* __restrict__ out)
{
    const int wave = threadIdx.x >> 6;          // 0..3
    const int lane = threadIdx.x & 63;          // 0..63
    const int row  = blockIdx.x * 4 + wave;     // 0..4095

    // ---- reduce max/min over x1 row (256 floats = 64 lanes x float4) ----
    const float4 v = reinterpret_cast<const float4*>(x1)[row * 64 + lane];
    float mx = fmaxf(fmaxf(v.x, v.y), fmaxf(v.z, v.w));
    float mn = fminf(fminf(v.x, v.y), fminf(v.z, v.w));
    #pragma unroll
    for (int off = 32; off > 0; off >>= 1) {
        mx = fmaxf(mx, __shfl_xor(mx, off));
        mn = fminf(mn, __shfl_xor(mn, off));
    }

    // ---- maxes = where(x0>=0, x0*mx, x0*mn) ----
    const float4 a = reinterpret_cast<const float4*>(x0)[row * 64 + lane];
    float4 r;
    r.x = a.x * (a.x >= 0.0f ? mx : mn);
    r.y = a.y * (a.y >= 0.0f ? mx : mn);
    r.z = a.z * (a.z >= 0.0f ? mx : mn);
    r.w = a.w * (a.w >= 0.0f ? mx : mn);

    float* orow = out + row * 384;
    *reinterpret_cast<float4*>(orow + lane * 4) = r;

    // ---- concat tail: copy x2 row (128 floats = 64 lanes x float2) ----
    const float2 c = reinterpret_cast<const float2*>(x2)[row * 64 + lane];
    *reinterpret_cast<float2*>(orow + 256 + lane * 2) = c;
}

extern "C" void kernel_launch(void* const* d_in, const int* in_sizes, int n_in,
                              void* d_out, int out_size, void* d_ws, size_t ws_size,
                              hipStream_t stream) {
    const float* x0 = (const float*)d_in[0];
    const float* x1 = (const float*)d_in[1];
    const float* x2 = (const float*)d_in[2];
    float* out = (float*)d_out;

    // B=4096 rows, 4 rows per 256-thread block
    pairwise_max_kernel<<<1024, 256, 0, stream>>>(x0, x1, x2, out);
}

// Round 2
// 10.246 us; speedup vs baseline: 1.0317x; 1.0317x over previous
//
#include <hip/hip_runtime.h>

// out[b, 0:256]  = x0[b,i] >= 0 ? x0[b,i]*max(x1[b,:]) : x0[b,i]*min(x1[b,:])
// out[b, 256:384] = x2[b, :]
// B=4096, D1=D2=256, F=128, out row stride = 384 floats.
//
// One wave (64 lanes) per row; 4 waves / 256-thread block; 1024 blocks
// -> 4096 waves = 16 waves/CU, all co-resident (max 32). Memory-level
// parallelism is TLP-saturated; this revision only reorders issue so all
// three VMEM loads are in flight before the dependent shuffle chain, and
// retires the independent x2 tail copy first.

__global__ __launch_bounds__(256) void pairwise_max_kernel(
    const float* __restrict__ x0,
    const float* __restrict__ x1,
    const float* __restrict__ x2,
    float* __restrict__ out)
{
    const int wave = threadIdx.x >> 6;          // 0..3
    const int lane = threadIdx.x & 63;          // 0..63
    const int row  = blockIdx.x * 4 + wave;     // 0..4095

    // ---- issue ALL loads before any dependent work ----
    const float4 v = reinterpret_cast<const float4*>(x1)[row * 64 + lane]; // 16B/lane
    const float4 a = reinterpret_cast<const float4*>(x0)[row * 64 + lane]; // 16B/lane
    const float2 c = reinterpret_cast<const float2*>(x2)[row * 64 + lane]; // 8B/lane

    float* orow = out + row * 384;

    // ---- independent tail copy retires first (no reduce dependency) ----
    *reinterpret_cast<float2*>(orow + 256 + lane * 2) = c;

    // ---- per-lane reduce (v_max3/v_min3-fusable) then 6-step butterfly ----
    float mx = fmaxf(fmaxf(v.x, v.y), fmaxf(v.z, v.w));
    float mn = fminf(fminf(v.x, v.y), fminf(v.z, v.w));
    #pragma unroll
    for (int off = 32; off > 0; off >>= 1) {
        mx = fmaxf(mx, __shfl_xor(mx, off));
        mn = fminf(mn, __shfl_xor(mn, off));
    }

    // ---- maxes = where(x0>=0, x0*mx, x0*mn) ----
    float4 r;
    r.x = a.x * (a.x >= 0.0f ? mx : mn);
    r.y = a.y * (a.y >= 0.0f ? mx : mn);
    r.z = a.z * (a.z >= 0.0f ? mx : mn);
    r.w = a.w * (a.w >= 0.0f ? mx : mn);
    *reinterpret_cast<float4*>(orow + lane * 4) = r;
}

extern "C" void kernel_launch(void* const* d_in, const int* in_sizes, int n_in,
                              void* d_out, int out_size, void* d_ws, size_t ws_size,
                              hipStream_t stream) {
    const float* x0 = (const float*)d_in[0];
    const float* x1 = (const float*)d_in[1];
    const float* x2 = (const float*)d_in[2];
    float* out = (float*)d_out;

    pairwise_max_kernel<<<1024, 256, 0, stream>>>(x0, x1, x2, out);
}